// Round 17
// baseline (265.022 us; speedup 1.0000x reference)
//
#include <hip/hip_runtime.h>
#include <hip/hip_bf16.h>
#include <stdint.h>

#define Bb   8
#define Tt   2048
#define Cdim 1024
#define BT   16384   // Bb*Tt
#define SLAB ((size_t)BT * Cdim)

// chunked WKV scan geometry (r9/r12-proven: ~27 us with packed kv)
#define NC   32            // chunks per chain
#define LCH  64            // Tt / NC
#define CSUB 32            // channels per block

typedef __attribute__((ext_vector_type(4))) float f32x4;
typedef __attribute__((ext_vector_type(8))) short bf16x8;

__device__ inline short f2bs(float f) {
    union { __hip_bfloat16 h; short s; } u;
    u.h = __float2bfloat16(f);
    return u.s;
}
__device__ inline float bs2f(short s) {
    union { short s; __hip_bfloat16 h; } u;
    u.s = s;
    return __bfloat162float(u.h);
}

#define GLOAD_LDS16(g, l) __builtin_amdgcn_global_load_lds( \
    (const __attribute__((address_space(1))) void*)(g),     \
    (__attribute__((address_space(3))) void*)(l), 16, 0, 0)

#define SBAR()      __builtin_amdgcn_s_barrier()

// ---------------------------------------------------------------------------
// prep_all: blocks [0,8192) do xmix lerp; blocks [8192,10240) do W->bf16.
// ---------------------------------------------------------------------------
__global__ __launch_bounds__(256) void prep_all(
    const float* __restrict__ x,
    const float* __restrict__ mk,
    const float* __restrict__ mv,
    const float* __restrict__ mr,
    const float* __restrict__ Wk, const float* __restrict__ Wv,
    const float* __restrict__ Wr, const float* __restrict__ Wo,
    short* __restrict__ xmix,
    short* __restrict__ wbf)
{
    int bid = blockIdx.x;
    if (bid < 8192) {
        int idx = bid * 256 + threadIdx.x;       // [0, BT*Cdim/8)
        int c8  = idx & (Cdim / 8 - 1);
        int m   = idx >> 7;                      // Cdim/8 == 128
        int c0  = c8 << 3;
        int t   = m & (Tt - 1);

        float xs[8], ps[8];
        const float4* xp = (const float4*)(x + (size_t)m * Cdim + c0);
        float4 xa = xp[0], xb = xp[1];
        xs[0]=xa.x; xs[1]=xa.y; xs[2]=xa.z; xs[3]=xa.w;
        xs[4]=xb.x; xs[5]=xb.y; xs[6]=xb.z; xs[7]=xb.w;
        if (t != 0) {
            const float4* pp = (const float4*)(x + (size_t)(m - 1) * Cdim + c0);
            float4 pa = pp[0], pb = pp[1];
            ps[0]=pa.x; ps[1]=pa.y; ps[2]=pa.z; ps[3]=pa.w;
            ps[4]=pb.x; ps[5]=pb.y; ps[6]=pb.z; ps[7]=pb.w;
        } else {
            #pragma unroll
            for (int j = 0; j < 8; ++j) ps[j] = 0.f;
        }

        const float* mixes[3] = {mk, mv, mr};
        #pragma unroll
        for (int z = 0; z < 3; ++z) {
            const float4* mp = (const float4*)(mixes[z] + c0);
            float4 ma = mp[0], mb = mp[1];
            float mm[8];
            mm[0]=ma.x; mm[1]=ma.y; mm[2]=ma.z; mm[3]=ma.w;
            mm[4]=mb.x; mm[5]=mb.y; mm[6]=mb.z; mm[7]=mb.w;
            bf16x8 o;
            #pragma unroll
            for (int j = 0; j < 8; ++j)
                o[j] = f2bs(ps[j] + mm[j] * (xs[j] - ps[j]));
            *(bf16x8*)(xmix + (size_t)z * SLAB + (size_t)m * Cdim + c0) = o;
        }
    } else {
        int idx = (bid - 8192) * 256 + threadIdx.x;  // [0, 4*C*C/8)
        int z   = idx >> 17;                         // C*C/8 == 131072
        int r   = idx & (Cdim * Cdim / 8 - 1);
        const float* src = (z == 0) ? Wk : (z == 1) ? Wv : (z == 2) ? Wr : Wo;
        const float4* sp = (const float4*)(src + (size_t)r * 8);
        float4 a = sp[0], b = sp[1];
        float v[8] = {a.x, a.y, a.z, a.w, b.x, b.y, b.z, b.w};
        bf16x8 o;
        #pragma unroll
        for (int j = 0; j < 8; ++j) o[j] = f2bs(v[j]);
        *(bf16x8*)(wbf + (size_t)z * Cdim * Cdim + (size_t)r * 8) = o;
    }
}

// ---------------------------------------------------------------------------
// gemm128 ROUND 17 (fused k/v/r only): m97-class structure — 128x128 tile,
// BK=64, 4 waves (2Mx2N, 64x64 each), SINGLE-buffered 32 KiB LDS ->
// ~3 blocks/CU (~164 VGPR), cross-block TLP hides the per-tile
// vmcnt(0)+barrier drain (m114 mechanism; guide: 128^2 = 912 TF vs
// 256^2 = 792 at this structure). Per K-tile:
// {stage A+B (8 gload_lds/thread) -> vmcnt(0) -> bar -> 16 ds_read_b128 +
// 32 MFMA 16x16x32 -> bar}. T2 chunk^row&7 swizzle (conflict-free, r14/r16
// verified for the 16x16 read pattern). Grid 3072 blocks = (24,128);
// kv-pair-adjacent XCD mapping (r12 L2 write-merge): XCD x owns yt in
// [16x,16x+16); s<256: pair=s>>1, z=s&1; s>=256: z=2. Bijective.
// z<2 -> interleaved kv bf16 (o0: kv[(row*C+cc)*2+z]); z=2 -> sigmoid(r)
// bf16 (o2). NO __launch_bounds__ min-wave coercion (r13: forcing spills).
// ---------------------------------------------------------------------------
__global__ __launch_bounds__(256) void gemm128(
    const short* __restrict__ Abase,
    const short* __restrict__ Wbase,
    void* __restrict__ o0, void* __restrict__ o2)
{
    __shared__ __align__(16) char lds[32768];    // A 16KB @0, B 16KB @16384

    const int tid  = threadIdx.x;
    const int lane = tid & 63;
    const int wv   = tid >> 6;
    const int wm   = wv >> 1, wn = wv & 1;       // 2 x 2 waves
    const int NT   = Cdim / 64;                  // 16 K-tiles

    int orig = blockIdx.y * 24 + blockIdx.x;     // 3072 blocks
    int xcd  = orig & 7;
    int s    = orig >> 3;                        // [0,384)
    int z, nt, yt;
    if (s < 256) { int pr = s >> 1; z = s & 1; nt = pr & 7; yt = xcd * 16 + (pr >> 3); }
    else         { int rm = s - 256; z = 2;     nt = rm & 7; yt = xcd * 16 + (rm >> 3); }

    const short* A  = Abase + (size_t)z * SLAB;
    const short* Bm = Wbase + (size_t)z * Cdim * Cdim;
    const int m0 = yt * 128;
    const int n0 = nt * 128;

    f32x4 acc[4][4] = {};

    // per-lane read offsets (bytes); rows are 128 B (64 bf16), 8 chunks of 16B
    const int lm = lane & 15, lq = lane >> 4, lb7 = lane & 7;  // lb7 == lm&7
    int ck[2];
    #pragma unroll
    for (int ks = 0; ks < 2; ++ks) ck[ks] = (((ks * 4 + lq) ^ lb7) << 4);
    int aoff[4];
    #pragma unroll
    for (int i = 0; i < 4; ++i) aoff[i] = (wm * 64 + i * 16 + lm) * 128;
    int boff[4];
    #pragma unroll
    for (int j = 0; j < 4; ++j) boff[j] = 16384 + (wn * 64 + j * 16 + lm) * 128;

    // stage one part (64 rows x 128 B = 8 KB): 2 gload_lds per thread.
    // parts 0,1 = A row-halves; 2,3 = B row-halves. Pre-swizzled source.
    const int rlo  = tid >> 3;                   // 0..31
    const int clog = (tid & 7) ^ (rlo & 7);      // rows rlo and rlo+32 share &7
    auto STAGE = [&](int tt, int part) {
        const short* mat = (part < 2) ? A : Bm;
        int rb = ((part < 2) ? m0 : n0) + ((part & 1) << 6);
        const short* g0 = mat + (size_t)(rb + rlo)      * Cdim + (tt << 6) + (clog << 3);
        const short* g1 = mat + (size_t)(rb + 32 + rlo) * Cdim + (tt << 6) + (clog << 3);
        char* l = lds + (part << 13) + tid * 16;
        GLOAD_LDS16(g0, l);
        GLOAD_LDS16(g1, l + 4096);
    };

    bf16x8 af[4][2], bf[4][2];

    #pragma unroll 1
    for (int kt = 0; kt < NT; ++kt) {
        STAGE(kt, 0); STAGE(kt, 1); STAGE(kt, 2); STAGE(kt, 3);
        asm volatile("s_waitcnt vmcnt(0)" ::: "memory");
        SBAR();

        #pragma unroll
        for (int i = 0; i < 4; ++i)
            #pragma unroll
            for (int ks = 0; ks < 2; ++ks)
                af[i][ks] = *(const bf16x8*)(lds + aoff[i] + ck[ks]);
        #pragma unroll
        for (int j = 0; j < 4; ++j)
            #pragma unroll
            for (int ks = 0; ks < 2; ++ks)
                bf[j][ks] = *(const bf16x8*)(lds + boff[j] + ck[ks]);

        #pragma unroll
        for (int ks = 0; ks < 2; ++ks)
            #pragma unroll
            for (int i = 0; i < 4; ++i)
                #pragma unroll
                for (int j = 0; j < 4; ++j)
                    acc[i][j] = __builtin_amdgcn_mfma_f32_16x16x32_bf16(
                        af[i][ks], bf[j][ks], acc[i][j], 0, 0, 0);

        SBAR();   // all reads of this tile done before next stage overwrites
    }

    // epilogue: C/D layout col = lane&15, row = (lane>>4)*4 + r  [m89]
    int col0 = n0 + wn * 64 + lm;
    int row0 = m0 + wm * 64 + (lq << 2);
    #pragma unroll
    for (int i = 0; i < 4; ++i) {
        #pragma unroll
        for (int j = 0; j < 4; ++j) {
            #pragma unroll
            for (int r = 0; r < 4; ++r) {
                int row = row0 + i * 16 + r;
                int cc  = col0 + j * 16;
                float vvv = acc[i][j][r];
                if (z == 2) {
                    ((short*)o2)[(size_t)row * Cdim + cc] =
                        f2bs(1.f / (1.f + __expf(-vvv)));
                } else {
                    ((short*)o0)[((size_t)row * Cdim + cc) * 2 + z] = f2bs(vvv);
                }
            }
        }
    }
}

// ---------------------------------------------------------------------------
// gemm256 (FUSED=0 path only; r16 structure, measured ~33 us): output GEMM.
// 256x256 tile, BK=64, 8 waves, 128 KiB dbuf LDS, single barrier per K-tile,
// z-major XCD mapping, T2 swizzle. f32 out.
// ---------------------------------------------------------------------------
__global__ __launch_bounds__(512, 2) void gemm256o(
    const short* __restrict__ A,
    const short* __restrict__ Bm,
    float* __restrict__ o0)
{
    __shared__ __align__(16) char lds[131072];

    const int tid  = threadIdx.x;
    const int lane = tid & 63;
    const int wv   = tid >> 6;
    const int wm   = wv >> 2, wn = wv & 3;       // 2 x 4 waves
    const int NT   = Cdim / 64;                  // 16 K-tiles

    int orig = blockIdx.y * 4 + blockIdx.x;
    int xcd  = orig & 7;
    int s    = orig >> 3;
    int nt = s & 3;
    int yt = xcd * 8 + (s >> 2);

    const int m0 = yt * 256;
    const int n0 = nt * 256;

    f32x4 acc[8][4] = {};

    const int lm = lane & 15, lq = lane >> 4, lb7 = lane & 7;
    int ck[2];
    #pragma unroll
    for (int ks = 0; ks < 2; ++ks) ck[ks] = (((ks * 4 + lq) ^ lb7) << 4);
    int aoff[8];
    #pragma unroll
    for (int i = 0; i < 8; ++i) aoff[i] = (i * 16 + lm) * 128;
    int boff[4];
    #pragma unroll
    for (int j = 0; j < 4; ++j) boff[j] = ((wn & 1) * 64 + j * 16 + lm) * 128;
    const int aReg = wm << 14;
    const int bReg = 32768 + ((wn >> 1) << 14);

    const int rlo  = tid >> 3;
    const int clog = (tid & 7) ^ (rlo & 7);
    auto STAGE = [&](int tt, int part) {
        const short* mat = (part < 2) ? A : Bm;
        int rb = ((part < 2) ? m0 : n0) + ((part & 1) << 7);
        const short* g0 = mat + (size_t)(rb + rlo)      * Cdim + (tt << 6) + (clog << 3);
        const short* g1 = mat + (size_t)(rb + 64 + rlo) * Cdim + (tt << 6) + (clog << 3);
        char* l = lds + ((tt & 1) << 16) + (part << 14) + tid * 16;
        GLOAD_LDS16(g0, l);
        GLOAD_LDS16(g1, l + 8192);
    };

    STAGE(0, 0); STAGE(0, 1); STAGE(0, 2); STAGE(0, 3);
    asm volatile("s_waitcnt vmcnt(0)" ::: "memory");
    SBAR();

    bf16x8 a0[4][2], a4[4][2], b01[2][2], b23[2][2];

    #pragma unroll 1
    for (int kt = 0; kt < NT; ++kt) {
        const char* base = lds + ((kt & 1) << 16);

        #pragma unroll
        for (int i = 0; i < 4; ++i)
            #pragma unroll
            for (int ks = 0; ks < 2; ++ks)
                a0[i][ks] = *(const bf16x8*)(base + aReg + aoff[i] + ck[ks]);
        #pragma unroll
        for (int j = 0; j < 2; ++j)
            #pragma unroll
            for (int ks = 0; ks < 2; ++ks)
                b01[j][ks] = *(const bf16x8*)(base + bReg + boff[j] + ck[ks]);
        #pragma unroll
        for (int i = 0; i < 4; ++i)
            #pragma unroll
            for (int ks = 0; ks < 2; ++ks)
                a4[i][ks] = *(const bf16x8*)(base + aReg + aoff[i + 4] + ck[ks]);
        #pragma unroll
        for (int j = 0; j < 2; ++j)
            #pragma unroll
            for (int ks = 0; ks < 2; ++ks)
                b23[j][ks] = *(const bf16x8*)(base + bReg + boff[j + 2] + ck[ks]);

        if (kt + 1 < NT) {
            STAGE(kt + 1, 0); STAGE(kt + 1, 1);
            STAGE(kt + 1, 2); STAGE(kt + 1, 3);
        }

        #pragma unroll
        for (int ks = 0; ks < 2; ++ks)
            #pragma unroll
            for (int i = 0; i < 4; ++i)
                #pragma unroll
                for (int j = 0; j < 2; ++j)
                    acc[i][j] = __builtin_amdgcn_mfma_f32_16x16x32_bf16(
                        a0[i][ks], b01[j][ks], acc[i][j], 0, 0, 0);
        #pragma unroll
        for (int ks = 0; ks < 2; ++ks)
            #pragma unroll
            for (int i = 0; i < 4; ++i)
                #pragma unroll
                for (int j = 0; j < 2; ++j)
                    acc[i + 4][j] = __builtin_amdgcn_mfma_f32_16x16x32_bf16(
                        a4[i][ks], b01[j][ks], acc[i + 4][j], 0, 0, 0);
        #pragma unroll
        for (int ks = 0; ks < 2; ++ks)
            #pragma unroll
            for (int i = 0; i < 4; ++i)
                #pragma unroll
                for (int j = 0; j < 2; ++j)
                    acc[i + 4][j + 2] = __builtin_amdgcn_mfma_f32_16x16x32_bf16(
                        a4[i][ks], b23[j][ks], acc[i + 4][j + 2], 0, 0, 0);
        #pragma unroll
        for (int ks = 0; ks < 2; ++ks)
            #pragma unroll
            for (int i = 0; i < 4; ++i)
                #pragma unroll
                for (int j = 0; j < 2; ++j)
                    acc[i][j + 2] = __builtin_amdgcn_mfma_f32_16x16x32_bf16(
                        a0[i][ks], b23[j][ks], acc[i][j + 2], 0, 0, 0);

        if (kt + 1 < NT) {
            asm volatile("s_waitcnt vmcnt(0)" ::: "memory");
            SBAR();
        }
    }

    int col0 = n0 + wn * 64 + lm;
    int row0 = m0 + wm * 128 + (lq << 2);
    #pragma unroll
    for (int i = 0; i < 8; ++i)
        #pragma unroll
        for (int j = 0; j < 4; ++j)
            #pragma unroll
            for (int r = 0; r < 4; ++r)
                o0[(size_t)(row0 + i * 16 + r) * Cdim + col0 + j * 16] =
                    acc[i][j][r];
}

// ---------------------------------------------------------------------------
// wkv_chunked (r9/r12 structure): chunked-parallel stable WKV scan.
// k,v packed as one dword per (channel,t); r PRE-SIGMOIDED bf16.
// Block: CSUB=32 channels x NC=32 chunks = 1024 threads; grid = Bb*Cdim/32.
// ---------------------------------------------------------------------------
__global__ __launch_bounds__(1024) void wkv_chunked(
    const int* __restrict__ kv, const short* __restrict__ srb,
    const float* __restrict__ w, const float* __restrict__ u,
    short* __restrict__ rwkv)
{
    __shared__ float sp[NC][CSUB];
    __shared__ float sq[NC][CSUB];
    __shared__ float so[NC][CSUB];

    int tid = threadIdx.x;
    int cl  = tid & (CSUB - 1);
    int ch  = tid >> 5;                 // chunk index 0..NC-1
    int b   = blockIdx.x >> 5;          // grid = Bb * (Cdim/CSUB) = 8*32
    int cg  = blockIdx.x & 31;
    int c   = cg * CSUB + cl;

    float wexp = -__expf(w[c]);
    float uu   = u[c];
    size_t coff = (size_t)b * Tt * Cdim + (size_t)(ch * LCH) * Cdim + c;

    // ---- phase 1: local chunk summary from zero state ----
    float p = 0.f, q = 0.f, o = -1e30f;
    #pragma unroll 8
    for (int t = 0; t < LCH; ++t) {
        size_t off = coff + (size_t)t * Cdim;
        int pk = kv[off];
        float kt = bs2f((short)(pk & 0xffff));
        float vt = bs2f((short)((unsigned)pk >> 16));
        float wo  = wexp + o;
        float no  = fmaxf(wo, kt);
        float A   = __expf(wo - no);
        float B2  = __expf(kt - no);
        p = A * p + B2 * vt;
        q = A * q + B2;
        o = no;
    }
    sp[ch][cl] = p; sq[ch][cl] = q; so[ch][cl] = o;
    __syncthreads();

    // ---- phase 2: exclusive combine-scan over chunks (1 thread / channel) ----
    if (tid < CSUB) {
        float Ld = wexp * (float)LCH;   // decay of o over a full chunk
        float cp = 0.f, cq = 0.f, co = -1e30f;
        for (int j = 0; j < NC; ++j) {
            float lp = sp[j][tid], lq = sq[j][tid], lo = so[j][tid];
            sp[j][tid] = cp; sq[j][tid] = cq; so[j][tid] = co;  // incoming state
            float od = co + Ld;
            float no = fmaxf(od, lo);
            float A  = __expf(od - no);
            float B2 = __expf(lo - no);
            cp = A * cp + B2 * lp;
            cq = A * cq + B2 * lq;
            co = no;
        }
    }
    __syncthreads();

    // ---- phase 3: outputs from incoming state ----
    p = sp[ch][cl]; q = sq[ch][cl]; o = so[ch][cl];
    #pragma unroll 8
    for (int t = 0; t < LCH; ++t) {
        size_t off = coff + (size_t)t * Cdim;
        int pk = kv[off];
        float kt = bs2f((short)(pk & 0xffff));
        float vt = bs2f((short)((unsigned)pk >> 16));
        float sr = bs2f(srb[off]);       // sigmoid already applied in GEMM

        float uk  = uu + kt;
        float no  = fmaxf(o, uk);
        float Aa  = __expf(o - no);
        float Bc  = __expf(uk - no);
        float out = (Aa * p + Bc * vt) / (Aa * q + Bc);

        float wo  = wexp + o;
        float no2 = fmaxf(wo, kt);
        float A2  = __expf(wo - no2);
        float B2  = __expf(kt - no2);
        p = A2 * p + B2 * vt;
        q = A2 * q + B2;
        o = no2;

        rwkv[off] = f2bs(sr * out);
    }
}

// ---------------------------------------------------------------------------
extern "C" void kernel_launch(void* const* d_in, const int* in_sizes, int n_in,
                              void* d_out, int out_size, void* d_ws, size_t ws_size,
                              hipStream_t stream)
{
    const float* x    = (const float*)d_in[0];
    const float* w    = (const float*)d_in[1];
    const float* u    = (const float*)d_in[2];
    const float* mixk = (const float*)d_in[3];
    const float* mixv = (const float*)d_in[4];
    const float* mixr = (const float*)d_in[5];
    const float* Wk   = (const float*)d_in[6];
    const float* Wv   = (const float*)d_in[7];
    const float* Wr   = (const float*)d_in[8];
    const float* Wo   = (const float*)d_in[9];

    char* ws = (char*)d_ws;
    short* xmix = (short*)ws;                        // 3 slabs bf16 = 96 MiB
    short* wbf  = (short*)(ws + 3 * SLAB * 2);       // 4*C*C bf16 = 8 MiB
    short* rbuf = (short*)(ws + 3 * SLAB * 2 + (size_t)4 * Cdim * Cdim * 2); // 32 MiB
    short* rwkv = (short*)ws;                        // reuses dead xmix slab 0
    int*   kvbf = (int*)d_out;                       // k,v interleaved: 64 MiB

    // single prep dispatch: 8192 xmix blocks + 2048 W blocks
    prep_all<<<8192 + 2048, 256, 0, stream>>>(x, mixk, mixv, mixr,
                                              Wk, Wv, Wr, Wo, xmix, wbf);

    // fused k/v/r GEMM: 128^2 m97-class, grid (24,128) = 3072 blocks
    dim3 gf(24, 128);
    gemm128<<<gf, 256, 0, stream>>>(xmix, wbf, kvbf, rbuf);

    wkv_chunked<<<Bb * (Cdim / CSUB), 1024, 0, stream>>>(kvbf, rbuf, w, u, rwkv);

    // output GEMM: 256^2, grid (4,64) = 256 blocks, f32 out
    dim3 go(Cdim / 256, BT / 256);
    gemm256o<<<go, 512, 0, stream>>>(rwkv, wbf + 3 * (size_t)Cdim * Cdim,
                                     (float*)d_out);
}

// Round 18
// 230.025 us; speedup vs baseline: 1.1521x; 1.1521x over previous
//
#include <hip/hip_runtime.h>
#include <hip/hip_bf16.h>
#include <stdint.h>

#define Bb   8
#define Tt   2048
#define Cdim 1024
#define BT   16384   // Bb*Tt
#define SLAB ((size_t)BT * Cdim)

// chunked WKV scan geometry (r9/r12-proven: ~27 us with packed kv)
#define NC   32            // chunks per chain
#define LCH  64            // Tt / NC
#define CSUB 32            // channels per block

typedef __attribute__((ext_vector_type(4))) float f32x4;
typedef __attribute__((ext_vector_type(8))) short bf16x8;

__device__ inline short f2bs(float f) {
    union { __hip_bfloat16 h; short s; } u;
    u.h = __float2bfloat16(f);
    return u.s;
}
__device__ inline float bs2f(short s) {
    union { short s; __hip_bfloat16 h; } u;
    u.s = s;
    return __bfloat162float(u.h);
}

#define GLOAD_LDS16(g, l) __builtin_amdgcn_global_load_lds( \
    (const __attribute__((address_space(1))) void*)(g),     \
    (__attribute__((address_space(3))) void*)(l), 16, 0, 0)

#define SBAR()      __builtin_amdgcn_s_barrier()

// ---------------------------------------------------------------------------
// prep_all: blocks [0,8192) do xmix lerp; blocks [8192,10240) do W->bf16.
// ---------------------------------------------------------------------------
__global__ __launch_bounds__(256) void prep_all(
    const float* __restrict__ x,
    const float* __restrict__ mk,
    const float* __restrict__ mv,
    const float* __restrict__ mr,
    const float* __restrict__ Wk, const float* __restrict__ Wv,
    const float* __restrict__ Wr, const float* __restrict__ Wo,
    short* __restrict__ xmix,
    short* __restrict__ wbf)
{
    int bid = blockIdx.x;
    if (bid < 8192) {
        int idx = bid * 256 + threadIdx.x;       // [0, BT*Cdim/8)
        int c8  = idx & (Cdim / 8 - 1);
        int m   = idx >> 7;                      // Cdim/8 == 128
        int c0  = c8 << 3;
        int t   = m & (Tt - 1);

        float xs[8], ps[8];
        const float4* xp = (const float4*)(x + (size_t)m * Cdim + c0);
        float4 xa = xp[0], xb = xp[1];
        xs[0]=xa.x; xs[1]=xa.y; xs[2]=xa.z; xs[3]=xa.w;
        xs[4]=xb.x; xs[5]=xb.y; xs[6]=xb.z; xs[7]=xb.w;
        if (t != 0) {
            const float4* pp = (const float4*)(x + (size_t)(m - 1) * Cdim + c0);
            float4 pa = pp[0], pb = pp[1];
            ps[0]=pa.x; ps[1]=pa.y; ps[2]=pa.z; ps[3]=pa.w;
            ps[4]=pb.x; ps[5]=pb.y; ps[6]=pb.z; ps[7]=pb.w;
        } else {
            #pragma unroll
            for (int j = 0; j < 8; ++j) ps[j] = 0.f;
        }

        const float* mixes[3] = {mk, mv, mr};
        #pragma unroll
        for (int z = 0; z < 3; ++z) {
            const float4* mp = (const float4*)(mixes[z] + c0);
            float4 ma = mp[0], mb = mp[1];
            float mm[8];
            mm[0]=ma.x; mm[1]=ma.y; mm[2]=ma.z; mm[3]=ma.w;
            mm[4]=mb.x; mm[5]=mb.y; mm[6]=mb.z; mm[7]=mb.w;
            bf16x8 o;
            #pragma unroll
            for (int j = 0; j < 8; ++j)
                o[j] = f2bs(ps[j] + mm[j] * (xs[j] - ps[j]));
            *(bf16x8*)(xmix + (size_t)z * SLAB + (size_t)m * Cdim + c0) = o;
        }
    } else {
        int idx = (bid - 8192) * 256 + threadIdx.x;  // [0, 4*C*C/8)
        int z   = idx >> 17;                         // C*C/8 == 131072
        int r   = idx & (Cdim * Cdim / 8 - 1);
        const float* src = (z == 0) ? Wk : (z == 1) ? Wv : (z == 2) ? Wr : Wo;
        const float4* sp = (const float4*)(src + (size_t)r * 8);
        float4 a = sp[0], b = sp[1];
        float v[8] = {a.x, a.y, a.z, a.w, b.x, b.y, b.z, b.w};
        bf16x8 o;
        #pragma unroll
        for (int j = 0; j < 8; ++j) o[j] = f2bs(v[j]);
        *(bf16x8*)(wbf + (size_t)z * Cdim * Cdim + (size_t)r * 8) = o;
    }
}

// ---------------------------------------------------------------------------
// gemm256 ROUND 18 = r16 (best banked: fused ~119.5 us, total 227.1) with
// STAGE issued BEFORE the fragment reads (free ~100 cy extra head start for
// the global loads; tile-end vmcnt(0) semantics unchanged).
// Structure: 256x256 tile, BK=64, 8 waves (2Mx4N), 128 KiB dbuf LDS, single
// barrier per K-tile. kv-pair-adjacent XCD mapping (r12: L2 write-merge,
// WRITE 171->98 MB), T2 chunk^row&7 swizzle (conflict-free for the 16x16
// read pattern; 32x32 conflicts — r15). 1 block/CU is a register wall:
// 128 VGPR + 128 AGPR acc = 256/wave (r13: forcing 2/CU spills, 1.27 ms).
// 128^2 tile regresses (r17: staging-bytes/FLOP doubles on a staging-bound
// kernel + occupancy never realized). Nine schedule variants plateau at
// 33-38% MfmaUtil; this is the best of them.
// FUSED: z<2 -> interleaved kv bf16 (o0), z=2 -> sigmoid(r) bf16 (o2).
// ---------------------------------------------------------------------------
template<int FUSED>
__global__ __launch_bounds__(512, 2) void gemm256(
    const short* __restrict__ Abase,
    const short* __restrict__ Wbase,
    void* __restrict__ o0, void* __restrict__ o2)
{
    __shared__ __align__(16) char lds[131072];

    const int tid  = threadIdx.x;
    const int lane = tid & 63;
    const int wv   = tid >> 6;
    const int wm   = wv >> 2, wn = wv & 3;       // 2 x 4 waves
    const int NT   = Cdim / 64;                  // 16 K-tiles

    int orig = blockIdx.y * (FUSED ? 12 : 4) + blockIdx.x;
    int xcd  = orig & 7;
    int s    = orig >> 3;
    int z, nt, yt;
    if (FUSED) {
        if (s < 64) { int pr = s >> 1; z = s & 1; nt = pr & 3; yt = xcd * 8 + (pr >> 2); }
        else        { int rm = s - 64; z = 2;     nt = rm & 3; yt = xcd * 8 + (rm >> 2); }
    } else {
        z  = 0;
        nt = s & 3;
        yt = xcd * 8 + (s >> 2);
    }

    const short* A  = Abase + (size_t)z * SLAB;
    const short* Bm = Wbase + (size_t)z * Cdim * Cdim;
    const int m0 = yt * 256;
    const int n0 = nt * 256;

    f32x4 acc[8][4] = {};

    // per-lane read offsets (bytes)
    const int lm = lane & 15, lq = lane >> 4, lb7 = lane & 7;
    int ck[2];
    #pragma unroll
    for (int ks = 0; ks < 2; ++ks) ck[ks] = (((ks * 4 + lq) ^ lb7) << 4);
    int aoff[8];
    #pragma unroll
    for (int i = 0; i < 8; ++i) aoff[i] = (i * 16 + lm) * 128;
    int boff[4];
    #pragma unroll
    for (int j = 0; j < 4; ++j) boff[j] = ((wn & 1) * 64 + j * 16 + lm) * 128;
    const int aReg = wm << 14;                   // A-lo / A-hi
    const int bReg = 32768 + ((wn >> 1) << 14);  // B-lo / B-hi

    // stage one half-tile (2 x gload_lds, pre-swizzled global source)
    const int rlo  = tid >> 3;                   // 0..63
    const int clog = (tid & 7) ^ (rlo & 7);
    auto STAGE = [&](int tt, int part) {
        const short* mat = (part < 2) ? A : Bm;
        int rb = ((part < 2) ? m0 : n0) + ((part & 1) << 7);
        const short* g0 = mat + (size_t)(rb + rlo)      * Cdim + (tt << 6) + (clog << 3);
        const short* g1 = mat + (size_t)(rb + 64 + rlo) * Cdim + (tt << 6) + (clog << 3);
        char* l = lds + ((tt & 1) << 16) + (part << 14) + tid * 16;
        GLOAD_LDS16(g0, l);
        GLOAD_LDS16(g1, l + 8192);
    };

    // prologue: stage tile 0, drain, barrier
    STAGE(0, 0); STAGE(0, 1); STAGE(0, 2); STAGE(0, 3);
    asm volatile("s_waitcnt vmcnt(0)" ::: "memory");
    SBAR();

    bf16x8 a0[4][2], a4[4][2], b01[2][2], b23[2][2];

    #pragma unroll 1
    for (int kt = 0; kt < NT; ++kt) {
        const char* base = lds + ((kt & 1) << 16);

        // stage the whole next tile FIRST (opposite buffer) — the loads get
        // the entire ds_read+MFMA span to land before the tile-end vmcnt(0)
        if (kt + 1 < NT) {
            STAGE(kt + 1, 0); STAGE(kt + 1, 1);
            STAGE(kt + 1, 2); STAGE(kt + 1, 3);
        }

        // issue ALL fragment reads for this tile (compiler schedules
        // counted lgkmcnt against the MFMAs below)
        #pragma unroll
        for (int i = 0; i < 4; ++i)
            #pragma unroll
            for (int ks = 0; ks < 2; ++ks)
                a0[i][ks] = *(const bf16x8*)(base + aReg + aoff[i] + ck[ks]);
        #pragma unroll
        for (int j = 0; j < 2; ++j)
            #pragma unroll
            for (int ks = 0; ks < 2; ++ks)
                b01[j][ks] = *(const bf16x8*)(base + bReg + boff[j] + ck[ks]);
        #pragma unroll
        for (int i = 0; i < 4; ++i)
            #pragma unroll
            for (int ks = 0; ks < 2; ++ks)
                a4[i][ks] = *(const bf16x8*)(base + aReg + aoff[i + 4] + ck[ks]);
        #pragma unroll
        for (int j = 0; j < 2; ++j)
            #pragma unroll
            for (int ks = 0; ks < 2; ++ks)
                b23[j][ks] = *(const bf16x8*)(base + bReg + boff[j + 2] + ck[ks]);

        #pragma unroll
        for (int ks = 0; ks < 2; ++ks)
            #pragma unroll
            for (int i = 0; i < 4; ++i)
                #pragma unroll
                for (int j = 0; j < 2; ++j)
                    acc[i][j] = __builtin_amdgcn_mfma_f32_16x16x32_bf16(
                        a0[i][ks], b01[j][ks], acc[i][j], 0, 0, 0);
        #pragma unroll
        for (int ks = 0; ks < 2; ++ks)
            #pragma unroll
            for (int i = 0; i < 4; ++i)
                #pragma unroll
                for (int j = 0; j < 2; ++j)
                    acc[i + 4][j] = __builtin_amdgcn_mfma_f32_16x16x32_bf16(
                        a4[i][ks], b01[j][ks], acc[i + 4][j], 0, 0, 0);
        #pragma unroll
        for (int ks = 0; ks < 2; ++ks)
            #pragma unroll
            for (int i = 0; i < 4; ++i)
                #pragma unroll
                for (int j = 0; j < 2; ++j)
                    acc[i + 4][j + 2] = __builtin_amdgcn_mfma_f32_16x16x32_bf16(
                        a4[i][ks], b23[j][ks], acc[i + 4][j + 2], 0, 0, 0);
        #pragma unroll
        for (int ks = 0; ks < 2; ++ks)
            #pragma unroll
            for (int i = 0; i < 4; ++i)
                #pragma unroll
                for (int j = 0; j < 2; ++j)
                    acc[i][j + 2] = __builtin_amdgcn_mfma_f32_16x16x32_bf16(
                        a0[i][ks], b23[j][ks], acc[i][j + 2], 0, 0, 0);

        // single tile-end sync: next buffer resident, then cross the barrier
        if (kt + 1 < NT) {
            asm volatile("s_waitcnt vmcnt(0)" ::: "memory");
            SBAR();
        }
    }

    // epilogue: C/D layout col = lane&15, row = (lane>>4)*4 + r  [m89]
    int col0 = n0 + wn * 64 + lm;
    int row0 = m0 + wm * 128 + (lq << 2);
    #pragma unroll
    for (int i = 0; i < 8; ++i) {
        #pragma unroll
        for (int j = 0; j < 4; ++j) {
            #pragma unroll
            for (int r = 0; r < 4; ++r) {
                int row = row0 + i * 16 + r;
                int cc  = col0 + j * 16;
                float vvv = acc[i][j][r];
                if (FUSED) {
                    if (z == 2) {
                        ((short*)o2)[(size_t)row * Cdim + cc] =
                            f2bs(1.f / (1.f + __expf(-vvv)));
                    } else {
                        ((short*)o0)[((size_t)row * Cdim + cc) * 2 + z] = f2bs(vvv);
                    }
                } else {
                    ((float*)o0)[(size_t)row * Cdim + cc] = vvv;
                }
            }
        }
    }
}

// ---------------------------------------------------------------------------
// wkv_chunked (r9/r12 structure): chunked-parallel stable WKV scan.
// k,v packed as one dword per (channel,t); r PRE-SIGMOIDED bf16.
// Block: CSUB=32 channels x NC=32 chunks = 1024 threads; grid = Bb*Cdim/32.
// ---------------------------------------------------------------------------
__global__ __launch_bounds__(1024) void wkv_chunked(
    const int* __restrict__ kv, const short* __restrict__ srb,
    const float* __restrict__ w, const float* __restrict__ u,
    short* __restrict__ rwkv)
{
    __shared__ float sp[NC][CSUB];
    __shared__ float sq[NC][CSUB];
    __shared__ float so[NC][CSUB];

    int tid = threadIdx.x;
    int cl  = tid & (CSUB - 1);
    int ch  = tid >> 5;                 // chunk index 0..NC-1
    int b   = blockIdx.x >> 5;          // grid = Bb * (Cdim/CSUB) = 8*32
    int cg  = blockIdx.x & 31;
    int c   = cg * CSUB + cl;

    float wexp = -__expf(w[c]);
    float uu   = u[c];
    size_t coff = (size_t)b * Tt * Cdim + (size_t)(ch * LCH) * Cdim + c;

    // ---- phase 1: local chunk summary from zero state ----
    float p = 0.f, q = 0.f, o = -1e30f;
    #pragma unroll 8
    for (int t = 0; t < LCH; ++t) {
        size_t off = coff + (size_t)t * Cdim;
        int pk = kv[off];
        float kt = bs2f((short)(pk & 0xffff));
        float vt = bs2f((short)((unsigned)pk >> 16));
        float wo  = wexp + o;
        float no  = fmaxf(wo, kt);
        float A   = __expf(wo - no);
        float B2  = __expf(kt - no);
        p = A * p + B2 * vt;
        q = A * q + B2;
        o = no;
    }
    sp[ch][cl] = p; sq[ch][cl] = q; so[ch][cl] = o;
    __syncthreads();

    // ---- phase 2: exclusive combine-scan over chunks (1 thread / channel) ----
    if (tid < CSUB) {
        float Ld = wexp * (float)LCH;   // decay of o over a full chunk
        float cp = 0.f, cq = 0.f, co = -1e30f;
        for (int j = 0; j < NC; ++j) {
            float lp = sp[j][tid], lq = sq[j][tid], lo = so[j][tid];
            sp[j][tid] = cp; sq[j][tid] = cq; so[j][tid] = co;  // incoming state
            float od = co + Ld;
            float no = fmaxf(od, lo);
            float A  = __expf(od - no);
            float B2 = __expf(lo - no);
            cp = A * cp + B2 * lp;
            cq = A * cq + B2 * lq;
            co = no;
        }
    }
    __syncthreads();

    // ---- phase 3: outputs from incoming state ----
    p = sp[ch][cl]; q = sq[ch][cl]; o = so[ch][cl];
    #pragma unroll 8
    for (int t = 0; t < LCH; ++t) {
        size_t off = coff + (size_t)t * Cdim;
        int pk = kv[off];
        float kt = bs2f((short)(pk & 0xffff));
        float vt = bs2f((short)((unsigned)pk >> 16));
        float sr = bs2f(srb[off]);       // sigmoid already applied in GEMM

        float uk  = uu + kt;
        float no  = fmaxf(o, uk);
        float Aa  = __expf(o - no);
        float Bc  = __expf(uk - no);
        float out = (Aa * p + Bc * vt) / (Aa * q + Bc);

        float wo  = wexp + o;
        float no2 = fmaxf(wo, kt);
        float A2  = __expf(wo - no2);
        float B2  = __expf(kt - no2);
        p = A2 * p + B2 * vt;
        q = A2 * q + B2;
        o = no2;

        rwkv[off] = f2bs(sr * out);
    }
}

// ---------------------------------------------------------------------------
extern "C" void kernel_launch(void* const* d_in, const int* in_sizes, int n_in,
                              void* d_out, int out_size, void* d_ws, size_t ws_size,
                              hipStream_t stream)
{
    const float* x    = (const float*)d_in[0];
    const float* w    = (const float*)d_in[1];
    const float* u    = (const float*)d_in[2];
    const float* mixk = (const float*)d_in[3];
    const float* mixv = (const float*)d_in[4];
    const float* mixr = (const float*)d_in[5];
    const float* Wk   = (const float*)d_in[6];
    const float* Wv   = (const float*)d_in[7];
    const float* Wr   = (const float*)d_in[8];
    const float* Wo   = (const float*)d_in[9];

    char* ws = (char*)d_ws;
    short* xmix = (short*)ws;                        // 3 slabs bf16 = 96 MiB
    short* wbf  = (short*)(ws + 3 * SLAB * 2);       // 4*C*C bf16 = 8 MiB
    short* rbuf = (short*)(ws + 3 * SLAB * 2 + (size_t)4 * Cdim * Cdim * 2); // 32 MiB
    short* rwkv = (short*)ws;                        // reuses dead xmix slab 0
    int*   kvbf = (int*)d_out;                       // k,v interleaved: 64 MiB

    // single prep dispatch: 8192 xmix blocks + 2048 W blocks
    prep_all<<<8192 + 2048, 256, 0, stream>>>(x, mixk, mixv, mixr,
                                              Wk, Wv, Wr, Wo, xmix, wbf);

    // fused k/v/r GEMM: grid (12,64) = 768 blocks; kv pair-adjacent mapping
    dim3 gf(12, BT / 256);
    gemm256<1><<<gf, 512, 0, stream>>>(xmix, wbf, kvbf, rbuf);

    wkv_chunked<<<Bb * (Cdim / CSUB), 1024, 0, stream>>>(kvbf, rbuf, w, u, rwkv);

    // output GEMM: grid (4,64) = 256 blocks, f32 out (overwrites dead kv)
    dim3 go(Cdim / 256, BT / 256);
    gemm256<0><<<go, 512, 0, stream>>>(rwkv, wbf + 3 * (size_t)Cdim * Cdim,
                                       (float*)d_out, nullptr);
}

// Round 19
// 226.464 us; speedup vs baseline: 1.1703x; 1.0157x over previous
//
#include <hip/hip_runtime.h>
#include <hip/hip_bf16.h>
#include <stdint.h>

#define Bb   8
#define Tt   2048
#define Cdim 1024
#define BT   16384   // Bb*Tt
#define SLAB ((size_t)BT * Cdim)

// chunked WKV scan geometry (r9/r12-proven: ~27 us with packed kv)
#define NC   32            // chunks per chain
#define LCH  64            // Tt / NC
#define CSUB 32            // channels per block

typedef __attribute__((ext_vector_type(4))) float f32x4;
typedef __attribute__((ext_vector_type(8))) short bf16x8;

__device__ inline short f2bs(float f) {
    union { __hip_bfloat16 h; short s; } u;
    u.h = __float2bfloat16(f);
    return u.s;
}
__device__ inline float bs2f(short s) {
    union { short s; __hip_bfloat16 h; } u;
    u.s = s;
    return __bfloat162float(u.h);
}

#define GLOAD_LDS16(g, l) __builtin_amdgcn_global_load_lds( \
    (const __attribute__((address_space(1))) void*)(g),     \
    (__attribute__((address_space(3))) void*)(l), 16, 0, 0)

#define SBAR()      __builtin_amdgcn_s_barrier()

// ---------------------------------------------------------------------------
// prep_all: blocks [0,8192) do xmix lerp; blocks [8192,10240) do W->bf16.
// ---------------------------------------------------------------------------
__global__ __launch_bounds__(256) void prep_all(
    const float* __restrict__ x,
    const float* __restrict__ mk,
    const float* __restrict__ mv,
    const float* __restrict__ mr,
    const float* __restrict__ Wk, const float* __restrict__ Wv,
    const float* __restrict__ Wr, const float* __restrict__ Wo,
    short* __restrict__ xmix,
    short* __restrict__ wbf)
{
    int bid = blockIdx.x;
    if (bid < 8192) {
        int idx = bid * 256 + threadIdx.x;       // [0, BT*Cdim/8)
        int c8  = idx & (Cdim / 8 - 1);
        int m   = idx >> 7;                      // Cdim/8 == 128
        int c0  = c8 << 3;
        int t   = m & (Tt - 1);

        float xs[8], ps[8];
        const float4* xp = (const float4*)(x + (size_t)m * Cdim + c0);
        float4 xa = xp[0], xb = xp[1];
        xs[0]=xa.x; xs[1]=xa.y; xs[2]=xa.z; xs[3]=xa.w;
        xs[4]=xb.x; xs[5]=xb.y; xs[6]=xb.z; xs[7]=xb.w;
        if (t != 0) {
            const float4* pp = (const float4*)(x + (size_t)(m - 1) * Cdim + c0);
            float4 pa = pp[0], pb = pp[1];
            ps[0]=pa.x; ps[1]=pa.y; ps[2]=pa.z; ps[3]=pa.w;
            ps[4]=pb.x; ps[5]=pb.y; ps[6]=pb.z; ps[7]=pb.w;
        } else {
            #pragma unroll
            for (int j = 0; j < 8; ++j) ps[j] = 0.f;
        }

        const float* mixes[3] = {mk, mv, mr};
        #pragma unroll
        for (int z = 0; z < 3; ++z) {
            const float4* mp = (const float4*)(mixes[z] + c0);
            float4 ma = mp[0], mb = mp[1];
            float mm[8];
            mm[0]=ma.x; mm[1]=ma.y; mm[2]=ma.z; mm[3]=ma.w;
            mm[4]=mb.x; mm[5]=mb.y; mm[6]=mb.z; mm[7]=mb.w;
            bf16x8 o;
            #pragma unroll
            for (int j = 0; j < 8; ++j)
                o[j] = f2bs(ps[j] + mm[j] * (xs[j] - ps[j]));
            *(bf16x8*)(xmix + (size_t)z * SLAB + (size_t)m * Cdim + c0) = o;
        }
    } else {
        int idx = (bid - 8192) * 256 + threadIdx.x;  // [0, 4*C*C/8)
        int z   = idx >> 17;                         // C*C/8 == 131072
        int r   = idx & (Cdim * Cdim / 8 - 1);
        const float* src = (z == 0) ? Wk : (z == 1) ? Wv : (z == 2) ? Wr : Wo;
        const float4* sp = (const float4*)(src + (size_t)r * 8);
        float4 a = sp[0], b = sp[1];
        float v[8] = {a.x, a.y, a.z, a.w, b.x, b.y, b.z, b.w};
        bf16x8 o;
        #pragma unroll
        for (int j = 0; j < 8; ++j) o[j] = f2bs(v[j]);
        *(bf16x8*)(wbf + (size_t)z * Cdim * Cdim + (size_t)r * 8) = o;
    }
}

// ---------------------------------------------------------------------------
// gemm256 (FINAL = r16, best measured: fused ~119.5 us, total 227.1).
// Structure: 256x256 tile, BK=64, 8 waves (2Mx4N), 128 KiB dbuf LDS, SINGLE
// barrier per K-tile: {issue all 24 ds_reads (buf kt) -> stage whole tile
// kt+1 (8 gload_lds, opposite buf) -> 64 MFMA 16x16x32 (compiler emits
// counted lgkmcnt) -> vmcnt(0) -> barrier}. kv-pair-adjacent XCD mapping
// (r12: k/v blocks of one tile co-resident per XCD -> interleaved half-
// sector stores merge in L2, WRITE 171->98 MB). T2 chunk^row&7 swizzle
// (conflict-free for the 16x16 read pattern; 32x32 conflicts 9.4M — r15).
// Register wall: 128 VGPR + 128 AGPR acc = 256/wave -> 1 block/CU is hard
// (r13: forcing 2/CU spills, 1.27 ms). 128^2 tile regresses (r17: staged
// bytes/FLOP doubles on a staging-bound kernel). setprio removed (m190:
// null-to-negative on lockstep structures). Stage-after-reads order (r18:
// stage-first contends LDS ports, -3%).
// FUSED: z<2 -> interleaved kv bf16 (o0), z=2 -> sigmoid(r) bf16 (o2).
// ---------------------------------------------------------------------------
template<int FUSED>
__global__ __launch_bounds__(512, 2) void gemm256(
    const short* __restrict__ Abase,
    const short* __restrict__ Wbase,
    void* __restrict__ o0, void* __restrict__ o2)
{
    __shared__ __align__(16) char lds[131072];

    const int tid  = threadIdx.x;
    const int lane = tid & 63;
    const int wv   = tid >> 6;
    const int wm   = wv >> 2, wn = wv & 3;       // 2 x 4 waves
    const int NT   = Cdim / 64;                  // 16 K-tiles

    int orig = blockIdx.y * (FUSED ? 12 : 4) + blockIdx.x;
    int xcd  = orig & 7;
    int s    = orig >> 3;
    int z, nt, yt;
    if (FUSED) {
        if (s < 64) { int pr = s >> 1; z = s & 1; nt = pr & 3; yt = xcd * 8 + (pr >> 2); }
        else        { int rm = s - 64; z = 2;     nt = rm & 3; yt = xcd * 8 + (rm >> 2); }
    } else {
        z  = 0;
        nt = s & 3;
        yt = xcd * 8 + (s >> 2);
    }

    const short* A  = Abase + (size_t)z * SLAB;
    const short* Bm = Wbase + (size_t)z * Cdim * Cdim;
    const int m0 = yt * 256;
    const int n0 = nt * 256;

    f32x4 acc[8][4] = {};

    // per-lane read offsets (bytes)
    const int lm = lane & 15, lq = lane >> 4, lb7 = lane & 7;
    int ck[2];
    #pragma unroll
    for (int ks = 0; ks < 2; ++ks) ck[ks] = (((ks * 4 + lq) ^ lb7) << 4);
    int aoff[8];
    #pragma unroll
    for (int i = 0; i < 8; ++i) aoff[i] = (i * 16 + lm) * 128;
    int boff[4];
    #pragma unroll
    for (int j = 0; j < 4; ++j) boff[j] = ((wn & 1) * 64 + j * 16 + lm) * 128;
    const int aReg = wm << 14;                   // A-lo / A-hi
    const int bReg = 32768 + ((wn >> 1) << 14);  // B-lo / B-hi

    // stage one half-tile (2 x gload_lds, pre-swizzled global source)
    const int rlo  = tid >> 3;                   // 0..63
    const int clog = (tid & 7) ^ (rlo & 7);
    auto STAGE = [&](int tt, int part) {
        const short* mat = (part < 2) ? A : Bm;
        int rb = ((part < 2) ? m0 : n0) + ((part & 1) << 7);
        const short* g0 = mat + (size_t)(rb + rlo)      * Cdim + (tt << 6) + (clog << 3);
        const short* g1 = mat + (size_t)(rb + 64 + rlo) * Cdim + (tt << 6) + (clog << 3);
        char* l = lds + ((tt & 1) << 16) + (part << 14) + tid * 16;
        GLOAD_LDS16(g0, l);
        GLOAD_LDS16(g1, l + 8192);
    };

    // prologue: stage tile 0, drain, barrier
    STAGE(0, 0); STAGE(0, 1); STAGE(0, 2); STAGE(0, 3);
    asm volatile("s_waitcnt vmcnt(0)" ::: "memory");
    SBAR();

    bf16x8 a0[4][2], a4[4][2], b01[2][2], b23[2][2];

    #pragma unroll 1
    for (int kt = 0; kt < NT; ++kt) {
        const char* base = lds + ((kt & 1) << 16);

        // issue ALL fragment reads for this tile (compiler schedules
        // counted lgkmcnt against the MFMAs below)
        #pragma unroll
        for (int i = 0; i < 4; ++i)
            #pragma unroll
            for (int ks = 0; ks < 2; ++ks)
                a0[i][ks] = *(const bf16x8*)(base + aReg + aoff[i] + ck[ks]);
        #pragma unroll
        for (int j = 0; j < 2; ++j)
            #pragma unroll
            for (int ks = 0; ks < 2; ++ks)
                b01[j][ks] = *(const bf16x8*)(base + bReg + boff[j] + ck[ks]);
        #pragma unroll
        for (int i = 0; i < 4; ++i)
            #pragma unroll
            for (int ks = 0; ks < 2; ++ks)
                a4[i][ks] = *(const bf16x8*)(base + aReg + aoff[i + 4] + ck[ks]);
        #pragma unroll
        for (int j = 0; j < 2; ++j)
            #pragma unroll
            for (int ks = 0; ks < 2; ++ks)
                b23[j][ks] = *(const bf16x8*)(base + bReg + boff[j + 2] + ck[ks]);

        // stage the whole next tile into the opposite buffer
        if (kt + 1 < NT) {
            STAGE(kt + 1, 0); STAGE(kt + 1, 1);
            STAGE(kt + 1, 2); STAGE(kt + 1, 3);
        }

        #pragma unroll
        for (int ks = 0; ks < 2; ++ks)
            #pragma unroll
            for (int i = 0; i < 4; ++i)
                #pragma unroll
                for (int j = 0; j < 2; ++j)
                    acc[i][j] = __builtin_amdgcn_mfma_f32_16x16x32_bf16(
                        a0[i][ks], b01[j][ks], acc[i][j], 0, 0, 0);
        #pragma unroll
        for (int ks = 0; ks < 2; ++ks)
            #pragma unroll
            for (int i = 0; i < 4; ++i)
                #pragma unroll
                for (int j = 0; j < 2; ++j)
                    acc[i + 4][j] = __builtin_amdgcn_mfma_f32_16x16x32_bf16(
                        a4[i][ks], b01[j][ks], acc[i + 4][j], 0, 0, 0);
        #pragma unroll
        for (int ks = 0; ks < 2; ++ks)
            #pragma unroll
            for (int i = 0; i < 4; ++i)
                #pragma unroll
                for (int j = 0; j < 2; ++j)
                    acc[i + 4][j + 2] = __builtin_amdgcn_mfma_f32_16x16x32_bf16(
                        a4[i][ks], b23[j][ks], acc[i + 4][j + 2], 0, 0, 0);
        #pragma unroll
        for (int ks = 0; ks < 2; ++ks)
            #pragma unroll
            for (int i = 0; i < 4; ++i)
                #pragma unroll
                for (int j = 0; j < 2; ++j)
                    acc[i][j + 2] = __builtin_amdgcn_mfma_f32_16x16x32_bf16(
                        a0[i][ks], b23[j][ks], acc[i][j + 2], 0, 0, 0);

        // single tile-end sync: next buffer resident, then cross the barrier
        if (kt + 1 < NT) {
            asm volatile("s_waitcnt vmcnt(0)" ::: "memory");
            SBAR();
        }
    }

    // epilogue: C/D layout col = lane&15, row = (lane>>4)*4 + r  [m89]
    int col0 = n0 + wn * 64 + lm;
    int row0 = m0 + wm * 128 + (lq << 2);
    #pragma unroll
    for (int i = 0; i < 8; ++i) {
        #pragma unroll
        for (int j = 0; j < 4; ++j) {
            #pragma unroll
            for (int r = 0; r < 4; ++r) {
                int row = row0 + i * 16 + r;
                int cc  = col0 + j * 16;
                float vvv = acc[i][j][r];
                if (FUSED) {
                    if (z == 2) {
                        ((short*)o2)[(size_t)row * Cdim + cc] =
                            f2bs(1.f / (1.f + __expf(-vvv)));
                    } else {
                        ((short*)o0)[((size_t)row * Cdim + cc) * 2 + z] = f2bs(vvv);
                    }
                } else {
                    ((float*)o0)[(size_t)row * Cdim + cc] = vvv;
                }
            }
        }
    }
}

// ---------------------------------------------------------------------------
// wkv_chunked (r9/r12 structure): chunked-parallel stable WKV scan.
// k,v packed as one dword per (channel,t); r PRE-SIGMOIDED bf16.
// Block: CSUB=32 channels x NC=32 chunks = 1024 threads; grid = Bb*Cdim/32.
// ---------------------------------------------------------------------------
__global__ __launch_bounds__(1024) void wkv_chunked(
    const int* __restrict__ kv, const short* __restrict__ srb,
    const float* __restrict__ w, const float* __restrict__ u,
    short* __restrict__ rwkv)
{
    __shared__ float sp[NC][CSUB];
    __shared__ float sq[NC][CSUB];
    __shared__ float so[NC][CSUB];

    int tid = threadIdx.x;
    int cl  = tid & (CSUB - 1);
    int ch  = tid >> 5;                 // chunk index 0..NC-1
    int b   = blockIdx.x >> 5;          // grid = Bb * (Cdim/CSUB) = 8*32
    int cg  = blockIdx.x & 31;
    int c   = cg * CSUB + cl;

    float wexp = -__expf(w[c]);
    float uu   = u[c];
    size_t coff = (size_t)b * Tt * Cdim + (size_t)(ch * LCH) * Cdim + c;

    // ---- phase 1: local chunk summary from zero state ----
    float p = 0.f, q = 0.f, o = -1e30f;
    #pragma unroll 8
    for (int t = 0; t < LCH; ++t) {
        size_t off = coff + (size_t)t * Cdim;
        int pk = kv[off];
        float kt = bs2f((short)(pk & 0xffff));
        float vt = bs2f((short)((unsigned)pk >> 16));
        float wo  = wexp + o;
        float no  = fmaxf(wo, kt);
        float A   = __expf(wo - no);
        float B2  = __expf(kt - no);
        p = A * p + B2 * vt;
        q = A * q + B2;
        o = no;
    }
    sp[ch][cl] = p; sq[ch][cl] = q; so[ch][cl] = o;
    __syncthreads();

    // ---- phase 2: exclusive combine-scan over chunks (1 thread / channel) ----
    if (tid < CSUB) {
        float Ld = wexp * (float)LCH;   // decay of o over a full chunk
        float cp = 0.f, cq = 0.f, co = -1e30f;
        for (int j = 0; j < NC; ++j) {
            float lp = sp[j][tid], lq = sq[j][tid], lo = so[j][tid];
            sp[j][tid] = cp; sq[j][tid] = cq; so[j][tid] = co;  // incoming state
            float od = co + Ld;
            float no = fmaxf(od, lo);
            float A  = __expf(od - no);
            float B2 = __expf(lo - no);
            cp = A * cp + B2 * lp;
            cq = A * cq + B2 * lq;
            co = no;
        }
    }
    __syncthreads();

    // ---- phase 3: outputs from incoming state ----
    p = sp[ch][cl]; q = sq[ch][cl]; o = so[ch][cl];
    #pragma unroll 8
    for (int t = 0; t < LCH; ++t) {
        size_t off = coff + (size_t)t * Cdim;
        int pk = kv[off];
        float kt = bs2f((short)(pk & 0xffff));
        float vt = bs2f((short)((unsigned)pk >> 16));
        float sr = bs2f(srb[off]);       // sigmoid already applied in GEMM

        float uk  = uu + kt;
        float no  = fmaxf(o, uk);
        float Aa  = __expf(o - no);
        float Bc  = __expf(uk - no);
        float out = (Aa * p + Bc * vt) / (Aa * q + Bc);

        float wo  = wexp + o;
        float no2 = fmaxf(wo, kt);
        float A2  = __expf(wo - no2);
        float B2  = __expf(kt - no2);
        p = A2 * p + B2 * vt;
        q = A2 * q + B2;
        o = no2;

        rwkv[off] = f2bs(sr * out);
    }
}

// ---------------------------------------------------------------------------
extern "C" void kernel_launch(void* const* d_in, const int* in_sizes, int n_in,
                              void* d_out, int out_size, void* d_ws, size_t ws_size,
                              hipStream_t stream)
{
    const float* x    = (const float*)d_in[0];
    const float* w    = (const float*)d_in[1];
    const float* u    = (const float*)d_in[2];
    const float* mixk = (const float*)d_in[3];
    const float* mixv = (const float*)d_in[4];
    const float* mixr = (const float*)d_in[5];
    const float* Wk   = (const float*)d_in[6];
    const float* Wv   = (const float*)d_in[7];
    const float* Wr   = (const float*)d_in[8];
    const float* Wo   = (const float*)d_in[9];

    char* ws = (char*)d_ws;
    short* xmix = (short*)ws;                        // 3 slabs bf16 = 96 MiB
    short* wbf  = (short*)(ws + 3 * SLAB * 2);       // 4*C*C bf16 = 8 MiB
    short* rbuf = (short*)(ws + 3 * SLAB * 2 + (size_t)4 * Cdim * Cdim * 2); // 32 MiB
    short* rwkv = (short*)ws;                        // reuses dead xmix slab 0
    int*   kvbf = (int*)d_out;                       // k,v interleaved: 64 MiB

    // single prep dispatch: 8192 xmix blocks + 2048 W blocks
    prep_all<<<8192 + 2048, 256, 0, stream>>>(x, mixk, mixv, mixr,
                                              Wk, Wv, Wr, Wo, xmix, wbf);

    // fused k/v/r GEMM: grid (12,64) = 768 blocks; kv pair-adjacent mapping
    dim3 gf(12, BT / 256);
    gemm256<1><<<gf, 512, 0, stream>>>(xmix, wbf, kvbf, rbuf);

    wkv_chunked<<<Bb * (Cdim / CSUB), 1024, 0, stream>>>(kvbf, rbuf, w, u, rwkv);

    // output GEMM: grid (4,64) = 256 blocks, f32 out (overwrites dead kv)
    dim3 go(Cdim / 256, BT / 256);
    gemm256<0><<<go, 512, 0, stream>>>(rwkv, wbf + 3 * (size_t)Cdim * Cdim,
                                       (float*)d_out, nullptr);
}